// Round 2
// 269.622 us; speedup vs baseline: 1.0192x; 1.0192x over previous
//
#include <hip/hip_runtime.h>
#include <stdint.h>

#define B_DIM 64
#define C_DIM 3
#define HM 512
#define WM_META 513
#define WM 512
#define OSIZE 224
#define N_TRIES 10
#define OX_UNITS (OSIZE / 4)                      // 56
#define UNITS_PER_B (C_DIM * OSIZE * OX_UNITS)    // 37,632 = 147 * 256
#define BLOCKS_PER_B (UNITS_PER_B / 256)          // 147
#define TBL_STRIDE (B_DIM * OSIZE)                // 14,336 elements per table
#define WS_NEEDED (6u * TBL_STRIDE * 4u)          // 344,064 bytes

typedef float f32x4_t __attribute__((ext_vector_type(4)));

// ---------------- Threefry-2x32 (20 rounds), exactly JAX's ----------------
__device__ __forceinline__ uint32_t rotl32(uint32_t v, int d) {
    return (v << d) | (v >> (32 - d));
}

__device__ __forceinline__ void threefry2x32(uint32_t k0, uint32_t k1,
                                             uint32_t x0, uint32_t x1,
                                             uint32_t& o0, uint32_t& o1) {
    const uint32_t ks0 = k0, ks1 = k1, ks2 = k0 ^ k1 ^ 0x1BD11BDAu;
    x0 += ks0; x1 += ks1;
    x0 += x1; x1 = rotl32(x1, 13); x1 ^= x0;
    x0 += x1; x1 = rotl32(x1, 15); x1 ^= x0;
    x0 += x1; x1 = rotl32(x1, 26); x1 ^= x0;
    x0 += x1; x1 = rotl32(x1,  6); x1 ^= x0;
    x0 += ks1; x1 += ks2 + 1u;
    x0 += x1; x1 = rotl32(x1, 17); x1 ^= x0;
    x0 += x1; x1 = rotl32(x1, 29); x1 ^= x0;
    x0 += x1; x1 = rotl32(x1, 16); x1 ^= x0;
    x0 += x1; x1 = rotl32(x1, 24); x1 ^= x0;
    x0 += ks2; x1 += ks0 + 2u;
    x0 += x1; x1 = rotl32(x1, 13); x1 ^= x0;
    x0 += x1; x1 = rotl32(x1, 15); x1 ^= x0;
    x0 += x1; x1 = rotl32(x1, 26); x1 ^= x0;
    x0 += x1; x1 = rotl32(x1,  6); x1 ^= x0;
    x0 += ks0; x1 += ks1 + 3u;
    x0 += x1; x1 = rotl32(x1, 17); x1 ^= x0;
    x0 += x1; x1 = rotl32(x1, 29); x1 ^= x0;
    x0 += x1; x1 = rotl32(x1, 16); x1 ^= x0;
    x0 += x1; x1 = rotl32(x1, 24); x1 ^= x0;
    x0 += ks1; x1 += ks2 + 4u;
    x0 += x1; x1 = rotl32(x1, 13); x1 ^= x0;
    x0 += x1; x1 = rotl32(x1, 15); x1 ^= x0;
    x0 += x1; x1 = rotl32(x1, 26); x1 ^= x0;
    x0 += x1; x1 = rotl32(x1,  6); x1 ^= x0;
    x0 += ks2; x1 += ks0 + 5u;
    o0 = x0; o1 = x1;
}

__device__ __forceinline__ uint32_t jax_bits_elem(uint32_t k0, uint32_t k1, int b) {
    uint32_t w0, w1;
    threefry2x32(k0, k1, 0u, (uint32_t)b, w0, w1);
    return w0 ^ w1;
}

__device__ __forceinline__ float bits_to_uniform(uint32_t bits, float lo, float hi) {
#pragma clang fp contract(off)
    uint32_t fb = (bits >> 9) | 0x3f800000u;
    float u = __uint_as_float(fb) - 1.0f;   // [0,1)
    float d = hi - lo;
    float v = u * d + lo;
    return fmaxf(lo, v);
}

// ---------------- Kernel A: per-image params + per-axis tables ------------
// Grid: 64 blocks (one per image b) x 256 threads. Lanes 0..40 run the RNG
// chains in parallel; all threads run the (cheap, redundant-within-block)
// selection; lanes 0..223 then emit one y-table entry and one x-table entry.
// ws layout (all [B_DIM][OSIZE], SoA):
//   int   ty0  @ ws + 0*TBL_STRIDE
//   int   ty1  @ ws + 1*TBL_STRIDE
//   float twy  @ ws + 2*TBL_STRIDE
//   int   tmx0 @ ws + 3*TBL_STRIDE   (flip folded in)
//   int   tmx1 @ ws + 4*TBL_STRIDE
//   float twx  @ ws + 5*TBL_STRIDE
__global__ void __launch_bounds__(256)
params_kernel(const float* __restrict__ x, float* __restrict__ ws) {
#pragma clang fp contract(off)
    __shared__ float u_lds[41];

    const int tid = threadIdx.x;
    const int b = blockIdx.x;

    // ---- parallel RNG phase (identical to validated kernel) ----
    if (tid < 41) {
        if (tid < 40) {
            int t = tid >> 2;      // try 0..9
            int q = tid & 3;       // key 0..3
            uint32_t kp0, kp1;
            threefry2x32(0u, 42u, 0u, 1u, kp0, kp1);
            uint32_t f0, f1;
            threefry2x32(kp0, kp1, 0u, (uint32_t)t, f0, f1);
            uint32_t kq0, kq1;
            threefry2x32(f0, f1, 0u, (uint32_t)q, kq0, kq1);
            uint32_t bits = jax_bits_elem(kq0, kq1, b);
            const float log_lo = -0.22314355131420976f;
            const float log_hi =  0.22314355131420976f;
            float lo = (q == 0) ? 0.1f : (q == 1) ? log_lo : 0.0f;
            float hi = (q == 0) ? 1.0f : (q == 1) ? log_hi : 1.0f;
            u_lds[tid] = bits_to_uniform(bits, lo, hi);
        } else {
            uint32_t kf0, kf1;
            threefry2x32(0u, 42u, 0u, 0u, kf0, kf1);
            uint32_t bits = jax_bits_elem(kf0, kf1, b);
            u_lds[40] = bits_to_uniform(bits, 0.0f, 1.0f);
        }
    }
    __syncthreads();

    // ---- selection (identical math/order to validated kernel) ----
    size_t base = (size_t)b * C_DIM * HM * WM_META;
    float Hf = x[base + (WM_META - 1)];
    float Wf = x[base + (size_t)HM * WM_META + (WM_META - 1)];
    float area = Hf * Wf;

    int flip = (u_lds[40] > 0.5f) ? 1 : 0;

    float fi = -1.0f, fj = -1.0f, fh = -1.0f, fw = -1.0f;
    bool success = false;
    for (int t = 0; t < N_TRIES; ++t) {
        float u1 = u_lds[t * 4 + 0];
        float u2 = u_lds[t * 4 + 1];
        float u3 = u_lds[t * 4 + 2];
        float u4 = u_lds[t * 4 + 3];

        float ta = area * u1;
        float aspect = expf(u2);
        float cw = rintf(sqrtf(ta * aspect));
        float ch = rintf(sqrtf(ta / aspect));

        bool valid = (cw > 0.0f) && (cw <= Wf) && (ch > 0.0f) && (ch <= Hf) && (!success);

        float max_i = fmaxf(Hf - ch + 1.0f, 1.0f);
        float max_j = fmaxf(Wf - cw + 1.0f, 1.0f);
        float ri = floorf(u3 * max_i);
        float rj = floorf(u4 * max_j);

        if (valid) { fh = ch; fw = cw; fi = ri; fj = rj; success = true; }
    }
    if (!success) {
        float in_ratio = Wf / Hf;
        float fbw = (in_ratio > 1.25f) ? rintf(Hf * 1.25f) : Wf;
        float fbh = (in_ratio < 0.8f)  ? rintf(Wf / 0.8f)  : Hf;
        fi = floorf((Hf - fbh) / 2.0f);
        fj = floorf((Wf - fbw) / 2.0f);
        fh = fbh; fw = fbw;
    }

    int pi = (int)fi, pj = (int)fj, ph = (int)fh, pw = (int)fw;

    if (tid < OSIZE) {
        // ---- y table entry (bit-identical to validated per-pixel math) ----
        float hf = (float)ph;
        int oy = tid;
        float ys = ((float)oy + 0.5f) * hf;
        ys = ys / 224.0f;
        ys = ys - 0.5f;
        ys = fminf(fmaxf(ys, 0.0f), hf - 1.0f);
        float y0f = floorf(ys);
        float wy = ys - y0f;
        int y0 = (int)y0f + pi;
        y0 = min(max(y0, 0), HM - 1);
        int yhi = min(max(pi + ph - 1, 0), HM - 1);
        int y1 = min(max(y0 + 1, 0), yhi);

        int*   ty0 = (int*)ws;
        int*   ty1 = (int*)(ws + TBL_STRIDE);
        float* twy = ws + 2 * TBL_STRIDE;
        int off = b * OSIZE + tid;
        ty0[off] = y0;
        ty1[off] = y1;
        twy[off] = wy;

        // ---- x table entry ----
        float wf = (float)pw;
        int ox = tid;
        float xs = ((float)ox + 0.5f) * wf;
        xs = xs / 224.0f;
        xs = xs - 0.5f;
        xs = fminf(fmaxf(xs, 0.0f), wf - 1.0f);
        float x0f = floorf(xs);
        float wx = xs - x0f;
        int x0 = (int)x0f + pj;
        x0 = min(max(x0, 0), WM - 1);
        int xhi = min(max(pj + pw - 1, 0), WM - 1);
        int x1 = min(max(x0 + 1, 0), xhi);

        int mx0 = flip ? (WM - x0) : x0;
        int mx1 = flip ? (WM - x1) : x1;

        int*   tmx0 = (int*)(ws + 3 * TBL_STRIDE);
        int*   tmx1 = (int*)(ws + 4 * TBL_STRIDE);
        float* twx  = ws + 5 * TBL_STRIDE;
        tmx0[off] = mx0;
        tmx1[off] = mx1;
        twx[off]  = wx;
    }
}

// ---------------- Kernel B: lean gather + lerp ----------------------------
// Grid: 64*147 = 9408 blocks x 256. Per thread: 3 scalar y-table loads,
// 3x16B x-table loads, 16 gathers, 3 lerps, one nontemporal 16B store.
__global__ void __launch_bounds__(256)
resize_kernel(const float* __restrict__ x, const float* __restrict__ ws,
              float* __restrict__ out) {
#pragma clang fp contract(off)
    const int tid = threadIdx.x;
    const int idx = blockIdx.x * 256 + tid;
    const int b = blockIdx.x / BLOCKS_PER_B;

    int oxu = idx % OX_UNITS;
    int tmp = idx / OX_UNITS;
    int oy = tmp % OSIZE;
    int c = (tmp / OSIZE) % C_DIM;

    const int*   ty0  = (const int*)ws;
    const int*   ty1  = (const int*)(ws + TBL_STRIDE);
    const float* twy  = ws + 2 * TBL_STRIDE;
    const int*   tmx0 = (const int*)(ws + 3 * TBL_STRIDE);
    const int*   tmx1 = (const int*)(ws + 4 * TBL_STRIDE);
    const float* twx  = ws + 5 * TBL_STRIDE;

    const int yoff = b * OSIZE + oy;
    const int y0 = ty0[yoff];
    const int y1 = ty1[yoff];
    const float wy = twy[yoff];

    const int xoff = b * OSIZE + oxu * 4;   // 16B-aligned by construction
    const int4   m0  = *reinterpret_cast<const int4*>(tmx0 + xoff);
    const int4   m1  = *reinterpret_cast<const int4*>(tmx1 + xoff);
    const float4 wxv = *reinterpret_cast<const float4*>(twx + xoff);

    const float* img  = x + ((size_t)(b * C_DIM + c)) * HM * WM_META;
    const float* row0 = img + (size_t)y0 * WM_META;
    const float* row1 = img + (size_t)y1 * WM_META;

    const int   mx0a[4] = {m0.x, m0.y, m0.z, m0.w};
    const int   mx1a[4] = {m1.x, m1.y, m1.z, m1.w};
    const float wxa[4]  = {wxv.x, wxv.y, wxv.z, wxv.w};

    float res[4];
#pragma unroll
    for (int k = 0; k < 4; ++k) {
        float g00 = row0[mx0a[k]];
        float g01 = row0[mx1a[k]];
        float g10 = row1[mx0a[k]];
        float g11 = row1[mx1a[k]];

        float top = (1.0f - wxa[k]) * g00 + wxa[k] * g01;
        float bot = (1.0f - wxa[k]) * g10 + wxa[k] * g11;
        res[k] = (1.0f - wy) * top + wy * bot;
    }

    f32x4_t v;
    v.x = res[0]; v.y = res[1]; v.z = res[2]; v.w = res[3];
    __builtin_nontemporal_store(v, reinterpret_cast<f32x4_t*>(out + (size_t)idx * 4));
}

// ---------------- Fallback: validated single fused kernel -----------------
__global__ void __launch_bounds__(256)
fused_kernel(const float* __restrict__ x, float* __restrict__ out) {
#pragma clang fp contract(off)
    __shared__ float u_lds[41];

    const int tid = threadIdx.x;
    const int b = blockIdx.x / BLOCKS_PER_B;

    if (tid < 41) {
        if (tid < 40) {
            int t = tid >> 2;
            int q = tid & 3;
            uint32_t kp0, kp1;
            threefry2x32(0u, 42u, 0u, 1u, kp0, kp1);
            uint32_t f0, f1;
            threefry2x32(kp0, kp1, 0u, (uint32_t)t, f0, f1);
            uint32_t kq0, kq1;
            threefry2x32(f0, f1, 0u, (uint32_t)q, kq0, kq1);
            uint32_t bits = jax_bits_elem(kq0, kq1, b);
            const float log_lo = -0.22314355131420976f;
            const float log_hi =  0.22314355131420976f;
            float lo = (q == 0) ? 0.1f : (q == 1) ? log_lo : 0.0f;
            float hi = (q == 0) ? 1.0f : (q == 1) ? log_hi : 1.0f;
            u_lds[tid] = bits_to_uniform(bits, lo, hi);
        } else {
            uint32_t kf0, kf1;
            threefry2x32(0u, 42u, 0u, 0u, kf0, kf1);
            uint32_t bits = jax_bits_elem(kf0, kf1, b);
            u_lds[40] = bits_to_uniform(bits, 0.0f, 1.0f);
        }
    }
    __syncthreads();

    size_t base = (size_t)b * C_DIM * HM * WM_META;
    float Hf = x[base + (WM_META - 1)];
    float Wf = x[base + (size_t)HM * WM_META + (WM_META - 1)];
    float area = Hf * Wf;

    int flip = (u_lds[40] > 0.5f) ? 1 : 0;

    float fi = -1.0f, fj = -1.0f, fh = -1.0f, fw = -1.0f;
    bool success = false;
    for (int t = 0; t < N_TRIES; ++t) {
        float u1 = u_lds[t * 4 + 0];
        float u2 = u_lds[t * 4 + 1];
        float u3 = u_lds[t * 4 + 2];
        float u4 = u_lds[t * 4 + 3];

        float ta = area * u1;
        float aspect = expf(u2);
        float cw = rintf(sqrtf(ta * aspect));
        float ch = rintf(sqrtf(ta / aspect));

        bool valid = (cw > 0.0f) && (cw <= Wf) && (ch > 0.0f) && (ch <= Hf) && (!success);

        float max_i = fmaxf(Hf - ch + 1.0f, 1.0f);
        float max_j = fmaxf(Wf - cw + 1.0f, 1.0f);
        float ri = floorf(u3 * max_i);
        float rj = floorf(u4 * max_j);

        if (valid) { fh = ch; fw = cw; fi = ri; fj = rj; success = true; }
    }
    if (!success) {
        float in_ratio = Wf / Hf;
        float fbw = (in_ratio > 1.25f) ? rintf(Hf * 1.25f) : Wf;
        float fbh = (in_ratio < 0.8f)  ? rintf(Wf / 0.8f)  : Hf;
        fi = floorf((Hf - fbh) / 2.0f);
        fj = floorf((Wf - fbw) / 2.0f);
        fh = fbh; fw = fbw;
    }

    int pi = (int)fi, pj = (int)fj, ph = (int)fh, pw = (int)fw;

    int idx = blockIdx.x * 256 + tid;
    int oxu = idx % OX_UNITS;
    int tmp = idx / OX_UNITS;
    int oy = tmp % OSIZE;
    tmp /= OSIZE;
    int c = tmp % C_DIM;

    float hf = (float)ph, wf = (float)pw;

    float ys = ((float)oy + 0.5f) * hf;
    ys = ys / 224.0f;
    ys = ys - 0.5f;
    ys = fminf(fmaxf(ys, 0.0f), hf - 1.0f);
    float y0f = floorf(ys);
    float wy = ys - y0f;
    int y0 = (int)y0f + pi;
    y0 = min(max(y0, 0), HM - 1);
    int yhi = min(max(pi + ph - 1, 0), HM - 1);
    int y1 = min(max(y0 + 1, 0), yhi);

    int xhi = min(max(pj + pw - 1, 0), WM - 1);

    const float* img  = x + ((size_t)(b * C_DIM + c)) * HM * WM_META;
    const float* row0 = img + (size_t)y0 * WM_META;
    const float* row1 = img + (size_t)y1 * WM_META;

    float res[4];
#pragma unroll
    for (int k = 0; k < 4; ++k) {
        int ox = oxu * 4 + k;
        float xs = ((float)ox + 0.5f) * wf;
        xs = xs / 224.0f;
        xs = xs - 0.5f;
        xs = fminf(fmaxf(xs, 0.0f), wf - 1.0f);
        float x0f = floorf(xs);
        float wx = xs - x0f;
        int x0 = (int)x0f + pj;
        x0 = min(max(x0, 0), WM - 1);
        int x1 = min(max(x0 + 1, 0), xhi);

        int mx0 = flip ? (WM - x0) : x0;
        int mx1 = flip ? (WM - x1) : x1;

        float g00 = row0[mx0];
        float g01 = row0[mx1];
        float g10 = row1[mx0];
        float g11 = row1[mx1];

        float top = (1.0f - wx) * g00 + wx * g01;
        float bot = (1.0f - wx) * g10 + wx * g11;
        res[k] = (1.0f - wy) * top + wy * bot;
    }

    float4 v = make_float4(res[0], res[1], res[2], res[3]);
    *reinterpret_cast<float4*>(out + (size_t)idx * 4) = v;
}

extern "C" void kernel_launch(void* const* d_in, const int* in_sizes, int n_in,
                              void* d_out, int out_size, void* d_ws, size_t ws_size,
                              hipStream_t stream) {
    const float* x = (const float*)d_in[0];
    float* out = (float*)d_out;

    const int blocks = B_DIM * BLOCKS_PER_B;  // 9408

    if (d_ws != nullptr && ws_size >= (size_t)WS_NEEDED) {
        float* ws = (float*)d_ws;
        params_kernel<<<B_DIM, 256, 0, stream>>>(x, ws);
        resize_kernel<<<blocks, 256, 0, stream>>>(x, ws, out);
    } else {
        // validated fallback path (bit-identical single kernel)
        fused_kernel<<<blocks, 256, 0, stream>>>(x, out);
    }
}